// Round 7
// baseline (2292.668 us; speedup 1.0000x reference)
//
#include <hip/hip_runtime.h>

typedef float f32x4 __attribute__((ext_vector_type(4)));
typedef short bf16x8 __attribute__((ext_vector_type(8)));

#define INV_TEMP 14.285714285714286f
#define M_REF    14.285714285714286f

static constexpr size_t OUT_PRED   = 0;
static constexpr size_t OUT_LOSS   = 409600;
static constexpr size_t OUT_LOGITS = 409601;
static constexpr size_t OUT_LPROTO = 268849153;
static constexpr size_t OUT_NEWQ   = 269258753;
static constexpr size_t OUT_NPROTO = 277647361;

__device__ __forceinline__ unsigned f2bf(float x){
  unsigned u = __float_as_uint(x);
  return (u + 0x7fffu + ((u >> 16) & 1u)) >> 16;   // RTNE
}

// ---------- prep: conv_qT (bid<1024) | conv_q (bid<1280) | lpos (else) ----------
__global__ __launch_bounds__(256) void prep_k(const float* __restrict__ q, const float* __restrict__ kk,
                                              const float* __restrict__ queue,
                                              unsigned short* __restrict__ qbf,
                                              unsigned short* __restrict__ qTbf,
                                              float* __restrict__ out, float* __restrict__ lposw){
  __shared__ float tile[128][65];
  const int bid = blockIdx.x, t = threadIdx.x;
  if (bid < 1024){                                  // queue [128][65536] -> qTbf [65536][128] bf16
    const int j0 = bid*64;
    for (int it=0; it<32; ++it){
      int idx = it*256 + t;
      int d = idx >> 6, j = idx & 63;
      tile[d][j] = queue[(size_t)d*65536 + j0 + j];
    }
    __syncthreads();
    for (int it=0; it<16; ++it){
      int pidx = it*256 + t;
      int j = pidx >> 6, d = (pidx & 63)*2;
      unsigned b0 = f2bf(tile[d][j]);
      unsigned b1 = f2bf(tile[d+1][j]);
      *(unsigned*)(qTbf + (size_t)(j0+j)*128 + d) = b0 | (b1 << 16);
    }
  } else if (bid < 1280){                           // q -> bf16
    int i = (bid-1024)*256 + t;
    const float4* q4 = (const float4*)q;
    float4 a = q4[2*i], b = q4[2*i+1];
    int4 st;
    st.x = (int)(f2bf(a.x) | (f2bf(a.y) << 16));
    st.y = (int)(f2bf(a.z) | (f2bf(a.w) << 16));
    st.z = (int)(f2bf(b.x) | (f2bf(b.y) << 16));
    st.w = (int)(f2bf(b.z) | (f2bf(b.w) << 16));
    ((int4*)qbf)[i] = st;
  } else {                                          // l_pos: 4 rows per block, 1 wave per row
    const int r = (bid-1280)*4 + (t>>6), l = t & 63;
    const float2* q2 = (const float2*)(q + (size_t)r*128);
    const float2* k2 = (const float2*)(kk + (size_t)r*128);
    float2 a = q2[l], b = k2[l];
    float s = a.x*b.x + a.y*b.y;
    #pragma unroll
    for (int o=1;o<64;o<<=1) s += __shfl_xor(s, o, 64);
    if (l == 0){
      float v = s * INV_TEMP;
      out[OUT_LOGITS + (size_t)r*65537] = v;
      lposw[r] = v;
    }
  }
}

// ---------- big GEMM: logits[:,1:] = (q @ queue)/TEMP, fused row sum-exp partials ----------
// R7: SAME kernel as R6 (best so far) with (a) launch_bounds 5 blocks/CU (LDS allows it),
// (b) gridDim.z = 3 PROBE — z>0 blocks redo identical work/stores (benign, deterministic)
// to surface this dispatch above the harness fills and capture its counters.
// dur_us - rest = 3*T_gemm decomposes the total.
__global__ __launch_bounds__(256, 5) void gemm_k(const unsigned short* __restrict__ qbf,
                                                 const unsigned short* __restrict__ qTbf,
                                                 float* __restrict__ out,
                                                 float* __restrict__ partials){
  __shared__ unsigned char smem[32768];            // B tile, XOR-swizzled
  const int cbr = blockIdx.x;
  const int cb  = ((cbr & 7) << 6) | (cbr >> 3);   // XCD-chunked
  const int rbg = blockIdx.y;
  const int t   = threadIdx.x;
  const unsigned char* bsrc = (const unsigned char*)qTbf + (size_t)cb*32768;
  #pragma unroll
  for (int i=0;i<8;++i){
    int X = i*4096 + t*16;
    int row = X >> 8, off = X & 255;
    int sw = (row << 8) | (off ^ ((row & 7) << 4));
    *(bf16x8*)(smem + sw) = *(const bf16x8*)(bsrc + X);
  }
  __syncthreads();
  const int l = t & 63, w = t >> 6;                // w = row-quadrant (32 rows)
  const int lrow = l & 15, lk = l >> 4;

  for (int ri=0; ri<8; ++ri){
    const int rb = rbg*8 + ri;
    const unsigned char* aP = (const unsigned char*)qbf + (size_t)rb*32768;
    f32x4 acc[2][8];
    #pragma unroll
    for (int m=0;m<2;++m)
      #pragma unroll
      for (int n=0;n<8;++n) acc[m][n] = (f32x4){0.f,0.f,0.f,0.f};
    #pragma unroll
    for (int kk2=0; kk2<4; ++kk2){
      const int koff = kk2*64 + lk*16;
      bf16x8 af[2], bfr[8];
      #pragma unroll
      for (int m=0;m<2;++m){
        int row = w*32 + m*16 + lrow;
        af[m] = *(const bf16x8*)(aP + (row << 8) + koff);    // global read
      }
      #pragma unroll
      for (int n=0;n<8;++n){
        int col = n*16 + lrow;
        bfr[n] = *(const bf16x8*)(smem + ((col << 8) | (koff ^ ((col & 7) << 4))));
      }
      #pragma unroll
      for (int m=0;m<2;++m)
        #pragma unroll
        for (int n=0;n<8;++n)
          acc[m][n] = __builtin_amdgcn_mfma_f32_16x16x32_bf16(af[m], bfr[n], acc[m][n], 0, 0, 0);
    }
    // epilogue — no barriers, plain stores (R2 microshape, measured 1.00x write amp)
    #pragma unroll
    for (int m=0;m<2;++m){
      #pragma unroll
      for (int r=0;r<4;++r){
        const size_t R = (size_t)rb*128 + w*32 + m*16 + lk*4 + r;    // global row
        float* p = out + OUT_LOGITS + R*65537 + 1 + (size_t)cb*128;
        float s = 0.f;
        #pragma unroll
        for (int n=0;n<8;++n){
          float v = acc[m][n][r] * INV_TEMP;
          p[n*16 + lrow] = v;
          s += __expf(v - M_REF);
        }
        #pragma unroll
        for (int o=1;o<16;o<<=1) s += __shfl_xor(s, o, 64);   // full 128-col row sum
        if (lrow == 0) partials[(size_t)cb*4096 + R] = s;
      }
    }
  }
}

// ---------- post: protos EMA (bid<100) | k6 (bid<4196) | rowsum (else) ----------
__global__ __launch_bounds__(128) void post_k(const float* __restrict__ q, const float* __restrict__ outp_in,
                                              const float* __restrict__ protos, const float* __restrict__ labels,
                                              const int* __restrict__ targets,
                                              const float* __restrict__ partials, const float* __restrict__ lposw,
                                              float* __restrict__ out, float* __restrict__ lcw,
                                              float* __restrict__ lpw, float* __restrict__ instw){
  __shared__ int   tg[4096];
  __shared__ int   mlist[4096];
  __shared__ int   cnt[128];
  __shared__ float red[128];
  __shared__ float qs[128];
  __shared__ float w2[2];
  const int bid = blockIdx.x, t = threadIdx.x;
  if (bid < 100){                                   // per-class prototype EMA via stable match list
    const int c = bid;
    for (int i=t;i<4096;i+=128) tg[i] = targets[i];
    __syncthreads();
    int myc = 0;
    #pragma unroll 4
    for (int i=0;i<32;++i) if (tg[t*32+i] == c) myc++;
    cnt[t] = myc; __syncthreads();
    // inclusive scan over 128 threads
    for (int s=1; s<128; s<<=1){
      int v = (t >= s) ? cnt[t-s] : 0;
      __syncthreads();
      cnt[t] += v;
      __syncthreads();
    }
    const int base = cnt[t] - myc;
    const int total = cnt[127];
    int k2 = base;
    for (int i=0;i<32;++i){
      int n = t*32 + i;
      if (tg[n] == c) mlist[k2++] = n;              // stable order: n ascending
    }
    __syncthreads();
    float val = protos[(size_t)c*128 + t];
    if (c != 0){
      for (int i=0;i<total;++i){
        int n = mlist[i];
        val = val*0.999f + 0.001f*q[(size_t)n*128 + t];
      }
    }
    red[t] = val*val; __syncthreads();
    #pragma unroll
    for (int s=64;s>0;s>>=1){ if (t < s) red[t] += red[t+s]; __syncthreads(); }
    float nrm = fmaxf(sqrtf(red[0]), 1e-12f);
    out[OUT_NPROTO + (size_t)c*128 + t] = val / nrm;
  } else if (bid < 4196){                           // logits_proto + both soft-CE rows + pred
    const int r = bid - 100;
    const int lane = t & 63, wid = t >> 6;
    qs[t] = q[(size_t)r*128 + t];
    __syncthreads();
    const bool act = t < 100;
    auto wmax = [&](float v)->float{
      #pragma unroll
      for (int o=1;o<64;o<<=1) v = fmaxf(v, __shfl_xor(v, o, 64));
      if (lane == 0) w2[wid] = v;
      __syncthreads();
      float rr = fmaxf(w2[0], w2[1]);
      __syncthreads();
      return rr;
    };
    auto wsum = [&](float v)->float{
      #pragma unroll
      for (int o=1;o<64;o<<=1) v += __shfl_xor(v, o, 64);
      if (lane == 0) w2[wid] = v;
      __syncthreads();
      float rr = w2[0] + w2[1];
      __syncthreads();
      return rr;
    };
    float p = 0.f;
    if (act){
      const float4* pr = (const float4*)(protos + (size_t)t*128);
      const float4* qv = (const float4*)qs;
      float s = 0.f;
      #pragma unroll 8
      for (int i=0;i<32;++i){ float4 a=qv[i], b=pr[i]; s += a.x*b.x + a.y*b.y + a.z*b.z + a.w*b.w; }
      p = s * INV_TEMP;
      out[OUT_LPROTO + (size_t)r*100 + t] = p;
    }
    const float lab = act ? labels[(size_t)r*100 + t] : 0.f;
    const float o   = act ? outp_in[(size_t)r*100 + t] : 0.f;
    float mx  = wmax(act ? p : -3.0e38f);
    float se  = wsum(act ? __expf(p - mx) : 0.f);
    float lse = mx + logf(se);
    float lpv = wsum(act ? lab * (p - lse) : 0.f);
    float mo   = wmax(act ? o : -3.0e38f);
    float seo  = wsum(act ? __expf(o - mo) : 0.f);
    float lseo = mo + logf(seo);
    float lcv  = wsum(act ? lab * (o - lseo) : 0.f);
    if (act) out[OUT_PRED + (size_t)r*100 + t] = (t > 0 && o >= mo) ? 1.f : 0.f;
    if (t == 0){ lpw[r] = lpv; lcw[r] = lcv; }
  } else {                                          // rowsum: inst log-softmax term
    const int r = (bid - 4196)*128 + t;
    float s = 0.f;
    for (int cbq=0; cbq<512; ++cbq) s += partials[(size_t)cbq*4096 + r];
    s += __expf(lposw[r] - M_REF);
    instw[r] = lposw[r] - M_REF - logf(s);
  }
}

// ---------- final scalar loss ----------
__global__ __launch_bounds__(256) void loss_k(const float* __restrict__ lcw, const float* __restrict__ lpw,
                                              const float* __restrict__ instw, float* __restrict__ out){
  __shared__ float red[256];
  const int t = threadIdx.x;
  float s = 0.f;
  for (int r=t;r<4096;r+=256) s += lcw[r] + lpw[r] + instw[r];
  red[t] = s; __syncthreads();
  for (int k2=128;k2>0;k2>>=1){ if (t<k2) red[t] += red[t+k2]; __syncthreads(); }
  if (t==0) out[OUT_LOSS] = -red[0] * (1.0f/4096.0f);
}

// ---------- new_queue: kt splice (bid<64) | copy (else) ----------
__global__ __launch_bounds__(256) void newq_k(const float* __restrict__ queue, const float* __restrict__ kk,
                                              const int* __restrict__ ptrp, float* __restrict__ out){
  __shared__ float tile[64][129];
  const int bid = blockIdx.x, t = threadIdx.x;
  const int ptr = *ptrp;
  if (bid < 64){                                    // k.T into columns [ptr, ptr+4096)
    const int jb = bid;
    for (int it=0; it<32; ++it){
      int idx = it*256 + t;
      int j = idx >> 7, d = idx & 127;
      tile[j][d] = kk[(size_t)(jb*64 + j)*128 + d];
    }
    __syncthreads();
    for (int it=0; it<32; ++it){
      int idx = it*256 + t;
      int d = idx >> 6, j = idx & 63;
      out[OUT_NEWQ + (size_t)d*65536 + (size_t)(ptr + jb*64 + j)] = tile[j][d];
    }
  } else {                                          // copy outside splice
    size_t tid = (size_t)(bid-64)*256 + t;
    for (size_t i=tid; i<(size_t)8388608; i += (size_t)4096*256){
      int j = (int)(i & 65535);
      int jm = j - ptr;
      if (jm >= 0 && jm < 4096) continue;
      out[OUT_NEWQ + i] = queue[i];
    }
  }
}

extern "C" void kernel_launch(void* const* d_in, const int* in_sizes, int n_in,
                              void* d_out, int out_size, void* d_ws, size_t ws_size,
                              hipStream_t stream){
  const float* q      = (const float*)d_in[0];
  const float* k      = (const float*)d_in[1];
  const float* outp   = (const float*)d_in[2];
  const float* queue  = (const float*)d_in[3];
  const float* protos = (const float*)d_in[4];
  const float* labels = (const float*)d_in[5];
  const int*   targets= (const int*)d_in[6];
  const int*   ptrp   = (const int*)d_in[7];
  float* out = (float*)d_out;

  // Scratch lives inside the new_queue OUTPUT region (32 MiB; we use ~25.1 MiB).
  // new_queue is written LAST, after every scratch consumer has finished.
  uintptr_t scr = (uintptr_t)(out + OUT_NEWQ);
  scr = (scr + 255) & ~(uintptr_t)255;
  unsigned short* qbf  = (unsigned short*)scr;                          // 1 MB
  unsigned short* qTbf = (unsigned short*)(scr + (1u<<20));             // 16 MB
  float* partials      = (float*)(scr + (1u<<20) + (16u<<20));          // 8 MB
  float* lposw         = (float*)(scr + 26214400u);                     // 16 KB
  float* lcw           = (float*)(scr + 26230784u);                     // 16 KB
  float* lpw           = (float*)(scr + 26247168u);                     // 16 KB
  float* instw         = (float*)(scr + 26263552u);                     // 16 KB

  prep_k <<<2304, 256, 0, stream>>>(q, k, queue, qbf, qTbf, out, lposw);
  gemm_k <<<dim3(512,4,3), 256, 0, stream>>>(qbf, qTbf, out, partials);  // z=3: probe
  post_k <<<4228, 128, 0, stream>>>(q, outp, protos, labels, targets, partials, lposw,
                                    out, lcw, lpw, instw);
  loss_k <<<1, 256, 0, stream>>>(lcw, lpw, instw, out);
  newq_k <<<4160, 256, 0, stream>>>(queue, k, ptrp, out);

  (void)in_sizes; (void)n_in; (void)d_ws; (void)ws_size; (void)out_size;
}

// Round 8
// 1603.974 us; speedup vs baseline: 1.4294x; 1.4294x over previous
//
#include <hip/hip_runtime.h>

typedef float f32x4 __attribute__((ext_vector_type(4)));
typedef short bf16x8 __attribute__((ext_vector_type(8)));
typedef float f32x4a __attribute__((ext_vector_type(4), aligned(4)));

#define INV_TEMP 14.285714285714286f
#define M_REF    14.285714285714286f

static constexpr size_t OUT_PRED   = 0;
static constexpr size_t OUT_LOSS   = 409600;
static constexpr size_t OUT_LOGITS = 409601;
static constexpr size_t OUT_LPROTO = 268849153;
static constexpr size_t OUT_NEWQ   = 269258753;
static constexpr size_t OUT_NPROTO = 277647361;

__device__ __forceinline__ unsigned f2bf(float x){
  unsigned u = __float_as_uint(x);
  return (u + 0x7fffu + ((u >> 16) & 1u)) >> 16;   // RTNE
}

// ---------- prep: conv_qT (bid<1024) | conv_q (bid<1280) | lpos (else) ----------
__global__ __launch_bounds__(256) void prep_k(const float* __restrict__ q, const float* __restrict__ kk,
                                              const float* __restrict__ queue,
                                              unsigned short* __restrict__ qbf,
                                              unsigned short* __restrict__ qTbf,
                                              float* __restrict__ out, float* __restrict__ lposw){
  __shared__ float tile[128][65];
  const int bid = blockIdx.x, t = threadIdx.x;
  if (bid < 1024){                                  // queue [128][65536] -> qTbf [65536][128] bf16
    const int j0 = bid*64;
    for (int it=0; it<32; ++it){
      int idx = it*256 + t;
      int d = idx >> 6, j = idx & 63;
      tile[d][j] = queue[(size_t)d*65536 + j0 + j];
    }
    __syncthreads();
    for (int it=0; it<16; ++it){
      int pidx = it*256 + t;
      int j = pidx >> 6, d = (pidx & 63)*2;
      unsigned b0 = f2bf(tile[d][j]);
      unsigned b1 = f2bf(tile[d+1][j]);
      *(unsigned*)(qTbf + (size_t)(j0+j)*128 + d) = b0 | (b1 << 16);
    }
  } else if (bid < 1280){                           // q -> bf16
    int i = (bid-1024)*256 + t;
    const float4* q4 = (const float4*)q;
    float4 a = q4[2*i], b = q4[2*i+1];
    int4 st;
    st.x = (int)(f2bf(a.x) | (f2bf(a.y) << 16));
    st.y = (int)(f2bf(a.z) | (f2bf(a.w) << 16));
    st.z = (int)(f2bf(b.x) | (f2bf(b.y) << 16));
    st.w = (int)(f2bf(b.z) | (f2bf(b.w) << 16));
    ((int4*)qbf)[i] = st;
  } else {                                          // l_pos: 4 rows per block, 1 wave per row
    const int r = (bid-1280)*4 + (t>>6), l = t & 63;
    const float2* q2 = (const float2*)(q + (size_t)r*128);
    const float2* k2 = (const float2*)(kk + (size_t)r*128);
    float2 a = q2[l], b = k2[l];
    float s = a.x*b.x + a.y*b.y;
    #pragma unroll
    for (int o=1;o<64;o<<=1) s += __shfl_xor(s, o, 64);
    if (l == 0){
      float v = s * INV_TEMP;
      out[OUT_LOGITS + (size_t)r*65537] = v;
      lposw[r] = v;
    }
  }
}

// ---------- big GEMM: logits[:,1:] = (q @ queue)/TEMP, fused row sum-exp partials ----------
// R8 theory (from R2/R5/R7 z=3 probes): write amp tracks A-fetch L2 churn, not store
// shape. Fix: (a) A reads via nontemporal_load (evict-first: A re-reads stop displacing
// partially-merged write lines; qbf 1MB stays MALL-resident). (b) swapped-operand MFMA
// mfma(B,A,acc) = (AB)^T fragment -> lane holds row=lane&15, col=lk*4+reg: 4 consecutive
// cols per reg -> float4 stores (4x fewer store instrs), row-sum = 2 shuffles.
__global__ __launch_bounds__(256, 5) void gemm_k(const unsigned short* __restrict__ qbf,
                                                 const unsigned short* __restrict__ qTbf,
                                                 float* __restrict__ out,
                                                 float* __restrict__ partials){
  __shared__ unsigned char smem[32768];            // B tile, XOR-swizzled
  const int cbr = blockIdx.x;
  const int cb  = ((cbr & 7) << 6) | (cbr >> 3);   // XCD-chunked
  const int rbg = blockIdx.y;
  const int t   = threadIdx.x;
  const unsigned char* bsrc = (const unsigned char*)qTbf + (size_t)cb*32768;
  #pragma unroll
  for (int i=0;i<8;++i){
    int X = i*4096 + t*16;
    int row = X >> 8, off = X & 255;
    int sw = (row << 8) | (off ^ ((row & 7) << 4));
    *(bf16x8*)(smem + sw) = *(const bf16x8*)(bsrc + X);
  }
  __syncthreads();
  const int l = t & 63, w = t >> 6;                // w = row-quadrant (32 rows)
  const int lrow = l & 15, lk = l >> 4;

  for (int ri=0; ri<8; ++ri){
    const int rb = rbg*8 + ri;
    const unsigned char* aP = (const unsigned char*)qbf + (size_t)rb*32768;
    f32x4 acc[2][8];
    #pragma unroll
    for (int m=0;m<2;++m)
      #pragma unroll
      for (int n=0;n<8;++n) acc[m][n] = (f32x4){0.f,0.f,0.f,0.f};
    #pragma unroll
    for (int kk2=0; kk2<4; ++kk2){
      const int koff = kk2*64 + lk*16;
      bf16x8 af[2], bfr[8];
      #pragma unroll
      for (int m=0;m<2;++m){
        int row = w*32 + m*16 + lrow;
        af[m] = __builtin_nontemporal_load((const bf16x8*)(aP + (row << 8) + koff));
      }
      #pragma unroll
      for (int n=0;n<8;++n){
        int col = n*16 + lrow;
        bfr[n] = *(const bf16x8*)(smem + ((col << 8) | (koff ^ ((col & 7) << 4))));
      }
      #pragma unroll
      for (int m=0;m<2;++m)
        #pragma unroll
        for (int n=0;n<8;++n)
          acc[m][n] = __builtin_amdgcn_mfma_f32_16x16x32_bf16(bfr[n], af[m], acc[m][n], 0, 0, 0);
    }
    // epilogue — transposed fragment: lane holds row = lrow, cols = n*16 + lk*4 + (0..3)
    #pragma unroll
    for (int m=0;m<2;++m){
      const size_t R = (size_t)rb*128 + w*32 + m*16 + lrow;        // global row
      float* p = out + OUT_LOGITS + R*65537 + 1 + (size_t)cb*128;
      float s = 0.f;
      #pragma unroll
      for (int n=0;n<8;++n){
        f32x4a vv;
        #pragma unroll
        for (int i=0;i<4;++i){
          float v = acc[m][n][i] * INV_TEMP;
          vv[i] = v;
          s += __expf(v - M_REF);
        }
        *(f32x4a*)(p + n*16 + lk*4) = vv;                          // plain store (no nt!)
      }
      s += __shfl_xor(s, 16, 64);
      s += __shfl_xor(s, 32, 64);                                  // full 128-col row sum
      if (lk == 0) partials[(size_t)cb*4096 + R] = s;              // 16 contiguous lanes
    }
  }
}

// ---------- post: protos EMA (bid<100) | k6 (bid<4196) | rowsum (else) ----------
__global__ __launch_bounds__(128) void post_k(const float* __restrict__ q, const float* __restrict__ outp_in,
                                              const float* __restrict__ protos, const float* __restrict__ labels,
                                              const int* __restrict__ targets,
                                              const float* __restrict__ partials, const float* __restrict__ lposw,
                                              float* __restrict__ out, float* __restrict__ lcw,
                                              float* __restrict__ lpw, float* __restrict__ instw){
  __shared__ int   tg[4096];
  __shared__ int   mlist[4096];
  __shared__ int   cnt[128];
  __shared__ float red[128];
  __shared__ float qs[128];
  __shared__ float w2[2];
  const int bid = blockIdx.x, t = threadIdx.x;
  if (bid < 100){                                   // per-class prototype EMA via stable match list
    const int c = bid;
    for (int i=t;i<4096;i+=128) tg[i] = targets[i];
    __syncthreads();
    int myc = 0;
    #pragma unroll 4
    for (int i=0;i<32;++i) if (tg[t*32+i] == c) myc++;
    cnt[t] = myc; __syncthreads();
    // inclusive scan over 128 threads
    for (int s=1; s<128; s<<=1){
      int v = (t >= s) ? cnt[t-s] : 0;
      __syncthreads();
      cnt[t] += v;
      __syncthreads();
    }
    const int base = cnt[t] - myc;
    const int total = cnt[127];
    int k2 = base;
    for (int i=0;i<32;++i){
      int n = t*32 + i;
      if (tg[n] == c) mlist[k2++] = n;              // stable order: n ascending
    }
    __syncthreads();
    float val = protos[(size_t)c*128 + t];
    if (c != 0){
      for (int i=0;i<total;++i){
        int n = mlist[i];
        val = val*0.999f + 0.001f*q[(size_t)n*128 + t];
      }
    }
    red[t] = val*val; __syncthreads();
    #pragma unroll
    for (int s=64;s>0;s>>=1){ if (t < s) red[t] += red[t+s]; __syncthreads(); }
    float nrm = fmaxf(sqrtf(red[0]), 1e-12f);
    out[OUT_NPROTO + (size_t)c*128 + t] = val / nrm;
  } else if (bid < 4196){                           // logits_proto + both soft-CE rows + pred
    const int r = bid - 100;
    const int lane = t & 63, wid = t >> 6;
    qs[t] = q[(size_t)r*128 + t];
    __syncthreads();
    const bool act = t < 100;
    auto wmax = [&](float v)->float{
      #pragma unroll
      for (int o=1;o<64;o<<=1) v = fmaxf(v, __shfl_xor(v, o, 64));
      if (lane == 0) w2[wid] = v;
      __syncthreads();
      float rr = fmaxf(w2[0], w2[1]);
      __syncthreads();
      return rr;
    };
    auto wsum = [&](float v)->float{
      #pragma unroll
      for (int o=1;o<64;o<<=1) v += __shfl_xor(v, o, 64);
      if (lane == 0) w2[wid] = v;
      __syncthreads();
      float rr = w2[0] + w2[1];
      __syncthreads();
      return rr;
    };
    float p = 0.f;
    if (act){
      const float4* pr = (const float4*)(protos + (size_t)t*128);
      const float4* qv = (const float4*)qs;
      float s = 0.f;
      #pragma unroll 8
      for (int i=0;i<32;++i){ float4 a=qv[i], b=pr[i]; s += a.x*b.x + a.y*b.y + a.z*b.z + a.w*b.w; }
      p = s * INV_TEMP;
      out[OUT_LPROTO + (size_t)r*100 + t] = p;
    }
    const float lab = act ? labels[(size_t)r*100 + t] : 0.f;
    const float o   = act ? outp_in[(size_t)r*100 + t] : 0.f;
    float mx  = wmax(act ? p : -3.0e38f);
    float se  = wsum(act ? __expf(p - mx) : 0.f);
    float lse = mx + logf(se);
    float lpv = wsum(act ? lab * (p - lse) : 0.f);
    float mo   = wmax(act ? o : -3.0e38f);
    float seo  = wsum(act ? __expf(o - mo) : 0.f);
    float lseo = mo + logf(seo);
    float lcv  = wsum(act ? lab * (o - lseo) : 0.f);
    if (act) out[OUT_PRED + (size_t)r*100 + t] = (t > 0 && o >= mo) ? 1.f : 0.f;
    if (t == 0){ lpw[r] = lpv; lcw[r] = lcv; }
  } else {                                          // rowsum: inst log-softmax term
    const int r = (bid - 4196)*128 + t;
    float s = 0.f;
    for (int cbq=0; cbq<512; ++cbq) s += partials[(size_t)cbq*4096 + r];
    s += __expf(lposw[r] - M_REF);
    instw[r] = lposw[r] - M_REF - logf(s);
  }
}

// ---------- final scalar loss ----------
__global__ __launch_bounds__(256) void loss_k(const float* __restrict__ lcw, const float* __restrict__ lpw,
                                              const float* __restrict__ instw, float* __restrict__ out){
  __shared__ float red[256];
  const int t = threadIdx.x;
  float s = 0.f;
  for (int r=t;r<4096;r+=256) s += lcw[r] + lpw[r] + instw[r];
  red[t] = s; __syncthreads();
  for (int k2=128;k2>0;k2>>=1){ if (t<k2) red[t] += red[t+k2]; __syncthreads(); }
  if (t==0) out[OUT_LOSS] = -red[0] * (1.0f/4096.0f);
}

// ---------- new_queue: kt splice (bid<64) | copy (else) ----------
__global__ __launch_bounds__(256) void newq_k(const float* __restrict__ queue, const float* __restrict__ kk,
                                              const int* __restrict__ ptrp, float* __restrict__ out){
  __shared__ float tile[64][129];
  const int bid = blockIdx.x, t = threadIdx.x;
  const int ptr = *ptrp;
  if (bid < 64){                                    // k.T into columns [ptr, ptr+4096)
    const int jb = bid;
    for (int it=0; it<32; ++it){
      int idx = it*256 + t;
      int j = idx >> 7, d = idx & 127;
      tile[j][d] = kk[(size_t)(jb*64 + j)*128 + d];
    }
    __syncthreads();
    for (int it=0; it<32; ++it){
      int idx = it*256 + t;
      int d = idx >> 6, j = idx & 63;
      out[OUT_NEWQ + (size_t)d*65536 + (size_t)(ptr + jb*64 + j)] = tile[j][d];
    }
  } else {                                          // copy outside splice
    size_t tid = (size_t)(bid-64)*256 + t;
    for (size_t i=tid; i<(size_t)8388608; i += (size_t)4096*256){
      int j = (int)(i & 65535);
      int jm = j - ptr;
      if (jm >= 0 && jm < 4096) continue;
      out[OUT_NEWQ + i] = queue[i];
    }
  }
}

extern "C" void kernel_launch(void* const* d_in, const int* in_sizes, int n_in,
                              void* d_out, int out_size, void* d_ws, size_t ws_size,
                              hipStream_t stream){
  const float* q      = (const float*)d_in[0];
  const float* k      = (const float*)d_in[1];
  const float* outp   = (const float*)d_in[2];
  const float* queue  = (const float*)d_in[3];
  const float* protos = (const float*)d_in[4];
  const float* labels = (const float*)d_in[5];
  const int*   targets= (const int*)d_in[6];
  const int*   ptrp   = (const int*)d_in[7];
  float* out = (float*)d_out;

  // Scratch lives inside the new_queue OUTPUT region (32 MiB; we use ~25.1 MiB).
  // new_queue is written LAST, after every scratch consumer has finished.
  uintptr_t scr = (uintptr_t)(out + OUT_NEWQ);
  scr = (scr + 255) & ~(uintptr_t)255;
  unsigned short* qbf  = (unsigned short*)scr;                          // 1 MB
  unsigned short* qTbf = (unsigned short*)(scr + (1u<<20));             // 16 MB
  float* partials      = (float*)(scr + (1u<<20) + (16u<<20));          // 8 MB
  float* lposw         = (float*)(scr + 26214400u);                     // 16 KB
  float* lcw           = (float*)(scr + 26230784u);                     // 16 KB
  float* lpw           = (float*)(scr + 26247168u);                     // 16 KB
  float* instw         = (float*)(scr + 26263552u);                     // 16 KB

  prep_k <<<2304, 256, 0, stream>>>(q, k, queue, qbf, qTbf, out, lposw);
  gemm_k <<<dim3(512,4), 256, 0, stream>>>(qbf, qTbf, out, partials);
  post_k <<<4228, 128, 0, stream>>>(q, outp, protos, labels, targets, partials, lposw,
                                    out, lcw, lpw, instw);
  loss_k <<<1, 256, 0, stream>>>(lcw, lpw, instw, out);
  newq_k <<<4160, 256, 0, stream>>>(queue, k, ptrp, out);

  (void)in_sizes; (void)n_in; (void)d_ws; (void)ws_size; (void)out_size;
}

// Round 9
// 407.990 us; speedup vs baseline: 5.6194x; 3.9314x over previous
//
#include <hip/hip_runtime.h>

typedef float f32x4 __attribute__((ext_vector_type(4)));
typedef short bf16x8 __attribute__((ext_vector_type(8)));

#define INV_TEMP 14.285714285714286f
#define M_REF    14.285714285714286f

static constexpr size_t OUT_PRED   = 0;
static constexpr size_t OUT_LOSS   = 409600;
static constexpr size_t OUT_LOGITS = 409601;
static constexpr size_t OUT_LPROTO = 268849153;
static constexpr size_t OUT_NEWQ   = 269258753;
static constexpr size_t OUT_NPROTO = 277647361;

__device__ __forceinline__ unsigned f2bf(float x){
  unsigned u = __float_as_uint(x);
  return (u + 0x7fffu + ((u >> 16) & 1u)) >> 16;   // RTNE
}

// ---------- prep: conv_qT (bid<1024) | conv_q (bid<1280) | lpos (else) ----------
__global__ __launch_bounds__(256) void prep_k(const float* __restrict__ q, const float* __restrict__ kk,
                                              const float* __restrict__ queue,
                                              unsigned short* __restrict__ qbf,
                                              unsigned short* __restrict__ qTbf,
                                              float* __restrict__ out, float* __restrict__ lposw){
  __shared__ float tile[128][65];
  const int bid = blockIdx.x, t = threadIdx.x;
  if (bid < 1024){                                  // queue [128][65536] -> qTbf [65536][128] bf16
    const int j0 = bid*64;
    for (int it=0; it<32; ++it){
      int idx = it*256 + t;
      int d = idx >> 6, j = idx & 63;
      tile[d][j] = queue[(size_t)d*65536 + j0 + j];
    }
    __syncthreads();
    for (int it=0; it<16; ++it){
      int pidx = it*256 + t;
      int j = pidx >> 6, d = (pidx & 63)*2;
      unsigned b0 = f2bf(tile[d][j]);
      unsigned b1 = f2bf(tile[d+1][j]);
      *(unsigned*)(qTbf + (size_t)(j0+j)*128 + d) = b0 | (b1 << 16);
    }
  } else if (bid < 1280){                           // q -> bf16
    int i = (bid-1024)*256 + t;
    const float4* q4 = (const float4*)q;
    float4 a = q4[2*i], b = q4[2*i+1];
    int4 st;
    st.x = (int)(f2bf(a.x) | (f2bf(a.y) << 16));
    st.y = (int)(f2bf(a.z) | (f2bf(a.w) << 16));
    st.z = (int)(f2bf(b.x) | (f2bf(b.y) << 16));
    st.w = (int)(f2bf(b.z) | (f2bf(b.w) << 16));
    ((int4*)qbf)[i] = st;
  } else {                                          // l_pos: 4 rows per block, 1 wave per row
    const int r = (bid-1280)*4 + (t>>6), l = t & 63;
    const float2* q2 = (const float2*)(q + (size_t)r*128);
    const float2* k2 = (const float2*)(kk + (size_t)r*128);
    float2 a = q2[l], b = k2[l];
    float s = a.x*b.x + a.y*b.y;
    #pragma unroll
    for (int o=1;o<64;o<<=1) s += __shfl_xor(s, o, 64);
    if (l == 0){
      float v = s * INV_TEMP;
      out[OUT_LOGITS + (size_t)r*65537] = v;
      lposw[r] = v;
    }
  }
}

// ---------- big GEMM: logits[:,1:] = (q @ queue)/TEMP, fused row sum-exp partials ----------
// R9: R2's proven-clean traffic pattern (A AND B burst-staged to LDS once per block ->
// measured WRITE amp 1.00x, FETCH 272MB) + 2x R2's occupancy: 512-thread one-shot
// 128x128 blocks, 64KB LDS, 2 blocks/CU = 16 waves/CU. ONE barrier total; epilogue
// is barrier-free (row-owning waves) so stores drain under other blocks' compute.
// Plain scalar stores (R2 microshape). NO nontemporal anything (R3/R8 lessons).
__global__ __launch_bounds__(512, 4) void gemm_k(const unsigned short* __restrict__ qbf,
                                                 const unsigned short* __restrict__ qTbf,
                                                 float* __restrict__ out,
                                                 float* __restrict__ partials){
  __shared__ unsigned char smem[65536];            // A 32KB | B 32KB, XOR-swizzled
  const int cbr = blockIdx.x;
  const int cb  = ((cbr & 7) << 6) | (cbr >> 3);   // XCD-chunked
  const int rb  = blockIdx.y;
  const int t   = threadIdx.x;
  const unsigned char* asrc = (const unsigned char*)qbf  + (size_t)rb*32768;
  const unsigned char* bsrc = (const unsigned char*)qTbf + (size_t)cb*32768;
  #pragma unroll
  for (int i=0;i<4;++i){
    int X = i*8192 + t*16;
    int row = X >> 8, off = X & 255;
    int sw = (row << 8) | (off ^ ((row & 7) << 4));
    *(bf16x8*)(smem + sw)         = *(const bf16x8*)(asrc + X);
    *(bf16x8*)(smem + 32768 + sw) = *(const bf16x8*)(bsrc + X);
  }
  __syncthreads();                                  // the only barrier
  const int l = t & 63, wid = t >> 6;               // 8 waves, wave owns 16 rows
  const int lrow = l & 15, lk = l >> 4;

  f32x4 acc[8];
  #pragma unroll
  for (int n=0;n<8;++n) acc[n] = (f32x4){0.f,0.f,0.f,0.f};
  #pragma unroll
  for (int kk2=0; kk2<4; ++kk2){
    const int koff = kk2*64 + lk*16;
    const int arow = wid*16 + lrow;
    bf16x8 af = *(const bf16x8*)(smem + ((arow << 8) | (koff ^ ((arow & 7) << 4))));
    bf16x8 bfr[8];
    #pragma unroll
    for (int n=0;n<8;++n){
      int col = n*16 + lrow;
      bfr[n] = *(const bf16x8*)(smem + 32768 + ((col << 8) | (koff ^ ((col & 7) << 4))));
    }
    #pragma unroll
    for (int n=0;n<8;++n)
      acc[n] = __builtin_amdgcn_mfma_f32_16x16x32_bf16(af, bfr[n], acc[n], 0, 0, 0);
  }
  // epilogue — no barriers, plain scalar stores (R2 microshape, measured amp 1.00x)
  #pragma unroll
  for (int r=0;r<4;++r){
    const size_t R = (size_t)rb*128 + wid*16 + lk*4 + r;         // global row
    float* p = out + OUT_LOGITS + R*65537 + 1 + (size_t)cb*128;
    float s = 0.f;
    #pragma unroll
    for (int n=0;n<8;++n){
      float v = acc[n][r] * INV_TEMP;
      p[n*16 + lrow] = v;
      s += __expf(v - M_REF);
    }
    #pragma unroll
    for (int o=1;o<16;o<<=1) s += __shfl_xor(s, o, 64);          // 16-lane row sum
    if (lrow == 0) partials[(size_t)cb*4096 + R] = s;
  }
}

// ---------- post: protos EMA (bid<100) | k6 (bid<4196) | rowsum (else) ----------
__global__ __launch_bounds__(128) void post_k(const float* __restrict__ q, const float* __restrict__ outp_in,
                                              const float* __restrict__ protos, const float* __restrict__ labels,
                                              const int* __restrict__ targets,
                                              const float* __restrict__ partials, const float* __restrict__ lposw,
                                              float* __restrict__ out, float* __restrict__ lcw,
                                              float* __restrict__ lpw, float* __restrict__ instw){
  __shared__ int   tg[4096];
  __shared__ int   mlist[4096];
  __shared__ int   cnt[128];
  __shared__ float red[128];
  __shared__ float qs[128];
  __shared__ float w2[2];
  const int bid = blockIdx.x, t = threadIdx.x;
  if (bid < 100){                                   // per-class prototype EMA via stable match list
    const int c = bid;
    for (int i=t;i<4096;i+=128) tg[i] = targets[i];
    __syncthreads();
    int myc = 0;
    #pragma unroll 4
    for (int i=0;i<32;++i) if (tg[t*32+i] == c) myc++;
    cnt[t] = myc; __syncthreads();
    // inclusive scan over 128 threads
    for (int s=1; s<128; s<<=1){
      int v = (t >= s) ? cnt[t-s] : 0;
      __syncthreads();
      cnt[t] += v;
      __syncthreads();
    }
    const int base = cnt[t] - myc;
    const int total = cnt[127];
    int k2 = base;
    for (int i=0;i<32;++i){
      int n = t*32 + i;
      if (tg[n] == c) mlist[k2++] = n;              // stable order: n ascending
    }
    __syncthreads();
    float val = protos[(size_t)c*128 + t];
    if (c != 0){
      for (int i=0;i<total;++i){
        int n = mlist[i];
        val = val*0.999f + 0.001f*q[(size_t)n*128 + t];
      }
    }
    red[t] = val*val; __syncthreads();
    #pragma unroll
    for (int s=64;s>0;s>>=1){ if (t < s) red[t] += red[t+s]; __syncthreads(); }
    float nrm = fmaxf(sqrtf(red[0]), 1e-12f);
    out[OUT_NPROTO + (size_t)c*128 + t] = val / nrm;
  } else if (bid < 4196){                           // logits_proto + both soft-CE rows + pred
    const int r = bid - 100;
    const int lane = t & 63, wid = t >> 6;
    qs[t] = q[(size_t)r*128 + t];
    __syncthreads();
    const bool act = t < 100;
    auto wmax = [&](float v)->float{
      #pragma unroll
      for (int o=1;o<64;o<<=1) v = fmaxf(v, __shfl_xor(v, o, 64));
      if (lane == 0) w2[wid] = v;
      __syncthreads();
      float rr = fmaxf(w2[0], w2[1]);
      __syncthreads();
      return rr;
    };
    auto wsum = [&](float v)->float{
      #pragma unroll
      for (int o=1;o<64;o<<=1) v += __shfl_xor(v, o, 64);
      if (lane == 0) w2[wid] = v;
      __syncthreads();
      float rr = w2[0] + w2[1];
      __syncthreads();
      return rr;
    };
    float p = 0.f;
    if (act){
      const float4* pr = (const float4*)(protos + (size_t)t*128);
      const float4* qv = (const float4*)qs;
      float s = 0.f;
      #pragma unroll 8
      for (int i=0;i<32;++i){ float4 a=qv[i], b=pr[i]; s += a.x*b.x + a.y*b.y + a.z*b.z + a.w*b.w; }
      p = s * INV_TEMP;
      out[OUT_LPROTO + (size_t)r*100 + t] = p;
    }
    const float lab = act ? labels[(size_t)r*100 + t] : 0.f;
    const float o   = act ? outp_in[(size_t)r*100 + t] : 0.f;
    float mx  = wmax(act ? p : -3.0e38f);
    float se  = wsum(act ? __expf(p - mx) : 0.f);
    float lse = mx + logf(se);
    float lpv = wsum(act ? lab * (p - lse) : 0.f);
    float mo   = wmax(act ? o : -3.0e38f);
    float seo  = wsum(act ? __expf(o - mo) : 0.f);
    float lseo = mo + logf(seo);
    float lcv  = wsum(act ? lab * (o - lseo) : 0.f);
    if (act) out[OUT_PRED + (size_t)r*100 + t] = (t > 0 && o >= mo) ? 1.f : 0.f;
    if (t == 0){ lpw[r] = lpv; lcw[r] = lcv; }
  } else {                                          // rowsum: inst log-softmax term
    const int r = (bid - 4196)*128 + t;
    float s = 0.f;
    for (int cbq=0; cbq<512; ++cbq) s += partials[(size_t)cbq*4096 + r];
    s += __expf(lposw[r] - M_REF);
    instw[r] = lposw[r] - M_REF - logf(s);
  }
}

// ---------- final scalar loss ----------
__global__ __launch_bounds__(256) void loss_k(const float* __restrict__ lcw, const float* __restrict__ lpw,
                                              const float* __restrict__ instw, float* __restrict__ out){
  __shared__ float red[256];
  const int t = threadIdx.x;
  float s = 0.f;
  for (int r=t;r<4096;r+=256) s += lcw[r] + lpw[r] + instw[r];
  red[t] = s; __syncthreads();
  for (int k2=128;k2>0;k2>>=1){ if (t<k2) red[t] += red[t+k2]; __syncthreads(); }
  if (t==0) out[OUT_LOSS] = -red[0] * (1.0f/4096.0f);
}

// ---------- new_queue: kt splice (bid<64) | copy (else) ----------
__global__ __launch_bounds__(256) void newq_k(const float* __restrict__ queue, const float* __restrict__ kk,
                                              const int* __restrict__ ptrp, float* __restrict__ out){
  __shared__ float tile[64][129];
  const int bid = blockIdx.x, t = threadIdx.x;
  const int ptr = *ptrp;
  if (bid < 64){                                    // k.T into columns [ptr, ptr+4096)
    const int jb = bid;
    for (int it=0; it<32; ++it){
      int idx = it*256 + t;
      int j = idx >> 7, d = idx & 127;
      tile[j][d] = kk[(size_t)(jb*64 + j)*128 + d];
    }
    __syncthreads();
    for (int it=0; it<32; ++it){
      int idx = it*256 + t;
      int d = idx >> 6, j = idx & 63;
      out[OUT_NEWQ + (size_t)d*65536 + (size_t)(ptr + jb*64 + j)] = tile[j][d];
    }
  } else {                                          // copy outside splice
    size_t tid = (size_t)(bid-64)*256 + t;
    for (size_t i=tid; i<(size_t)8388608; i += (size_t)4096*256){
      int j = (int)(i & 65535);
      int jm = j - ptr;
      if (jm >= 0 && jm < 4096) continue;
      out[OUT_NEWQ + i] = queue[i];
    }
  }
}

extern "C" void kernel_launch(void* const* d_in, const int* in_sizes, int n_in,
                              void* d_out, int out_size, void* d_ws, size_t ws_size,
                              hipStream_t stream){
  const float* q      = (const float*)d_in[0];
  const float* k      = (const float*)d_in[1];
  const float* outp   = (const float*)d_in[2];
  const float* queue  = (const float*)d_in[3];
  const float* protos = (const float*)d_in[4];
  const float* labels = (const float*)d_in[5];
  const int*   targets= (const int*)d_in[6];
  const int*   ptrp   = (const int*)d_in[7];
  float* out = (float*)d_out;

  // Scratch lives inside the new_queue OUTPUT region (32 MiB; we use ~25.1 MiB).
  // new_queue is written LAST, after every scratch consumer has finished.
  uintptr_t scr = (uintptr_t)(out + OUT_NEWQ);
  scr = (scr + 255) & ~(uintptr_t)255;
  unsigned short* qbf  = (unsigned short*)scr;                          // 1 MB
  unsigned short* qTbf = (unsigned short*)(scr + (1u<<20));             // 16 MB
  float* partials      = (float*)(scr + (1u<<20) + (16u<<20));          // 8 MB
  float* lposw         = (float*)(scr + 26214400u);                     // 16 KB
  float* lcw           = (float*)(scr + 26230784u);                     // 16 KB
  float* lpw           = (float*)(scr + 26247168u);                     // 16 KB
  float* instw         = (float*)(scr + 26263552u);                     // 16 KB

  prep_k <<<2304, 256, 0, stream>>>(q, k, queue, qbf, qTbf, out, lposw);
  gemm_k <<<dim3(512,32), 512, 0, stream>>>(qbf, qTbf, out, partials);
  post_k <<<4228, 128, 0, stream>>>(q, outp, protos, labels, targets, partials, lposw,
                                    out, lcw, lpw, instw);
  loss_k <<<1, 256, 0, stream>>>(lcw, lpw, instw, out);
  newq_k <<<4160, 256, 0, stream>>>(queue, k, ptrp, out);

  (void)in_sizes; (void)n_in; (void)d_ws; (void)ws_size; (void)out_size;
}